// Round 14
// baseline (121.000 us; speedup 1.0000x reference)
//
#include <hip/hip_runtime.h>

// out = x @ Wv^T  (T=1 linear-attention read/scale cancels exactly; verified
// passing r2/4/6/10). M=64 N=2048 K=2048 f32.
//
// r11: revert to r4's proven loop shape (x and W global->reg, block-common
// W octet shared by 4 waves -> L1 hits, full unroll -> compiler builds a
// deep vmcnt pipeline). Two structural changes vs r4:
//  1. K-split x2 (grid 1024): 12 waves/CU instead of 8 (grid was the cap).
//     Partials to ws, combined by a tiny second kernel (atomics write
//     through to HBM at 32B/op -- measured r2 -- so no atomics).
//  2. LDS reduce replaced by in-register shfl_xor butterfly transpose-
//     reduce (63 shfl + 63 add, in-place halving) -> LDS=0, no barriers.
// XCD swizzle: all 4 blocks (2 b-halves x 2 k-halves) of one n-octet group
// land on one XCD; each XCD's W working set = 2MB, L2-resident.

#define ND 2048
#define KD 2048
#define K4 (KD / 4)  // 512

// ---- main GEMM, K-split: NI k4-iters starting at kbase ----
template <int NI>
__device__ __forceinline__ void gemm_body(const float* __restrict__ x,
                                          const float* __restrict__ Wv,
                                          float* __restrict__ dst,
                                          int n0, int b0, int kbase, int lane) {
    const float4* __restrict__ xq = (const float4*)x;
    const float4* __restrict__ wq = (const float4*)Wv;

    float acc[64];  // acc[bb*8+nn]
#pragma unroll
    for (int j = 0; j < 64; ++j) acc[j] = 0.0f;

#pragma unroll
    for (int i = 0; i < NI; ++i) {
        const int k4 = kbase + (i << 6) + lane;
        float4 xr[8], wr[8];
#pragma unroll
        for (int bb = 0; bb < 8; ++bb)
            xr[bb] = xq[(size_t)(b0 + bb) * K4 + k4];
#pragma unroll
        for (int nn = 0; nn < 8; ++nn)
            wr[nn] = wq[(size_t)(n0 + nn) * K4 + k4];
#pragma unroll
        for (int bb = 0; bb < 8; ++bb)
#pragma unroll
            for (int nn = 0; nn < 8; ++nn) {
                float a = acc[bb * 8 + nn];
                a = fmaf(xr[bb].x, wr[nn].x, a);
                a = fmaf(xr[bb].y, wr[nn].y, a);
                a = fmaf(xr[bb].z, wr[nn].z, a);
                a = fmaf(xr[bb].w, wr[nn].w, a);
                acc[bb * 8 + nn] = a;
            }
    }

    // In-register butterfly transpose-reduce: after stage s, acc[u] holds
    // the sum over this lane's 2^(s+1)-aligned lane group of original
    // index j=(u<<(s+1))|(lane&(2^(s+1)-1)). After 6 stages lane j holds
    // the all-64-lane sum of acc[j].  (writes at u after reads at 2u,2u+1)
#pragma unroll
    for (int s = 0; s < 6; ++s) {
        const int bit = (lane >> s) & 1;
#pragma unroll
        for (int u = 0; u < (64 >> (s + 1)); ++u) {
            float snd = bit ? acc[2 * u] : acc[2 * u + 1];
            float kep = bit ? acc[2 * u + 1] : acc[2 * u];
            acc[u] = kep + __shfl_xor(snd, 1 << s, 64);
        }
    }

    dst[(size_t)(b0 + (lane >> 3)) * ND + n0 + (lane & 7)] = acc[0];
}

__global__ __launch_bounds__(256, 3)
void vgemm_ks(const float* __restrict__ x, const float* __restrict__ Wv,
              float* __restrict__ part) {
    const int lane = threadIdx.x & 63;
    const int wid  = threadIdx.x >> 6;          // 0..3
    const int bid  = blockIdx.x;                // 0..1023
    const int xcd  = bid & 7;
    const int r    = bid >> 3;                  // 0..127
    const int nO   = xcd * 32 + (r & 31);       // 0..255; same nO group -> same XCD
    const int bh   = (r >> 5) & 1;              // b-half
    const int kh   = r >> 6;                    // k-half
    gemm_body<4>(x, Wv, part + (size_t)kh * (64 * ND),
                 nO * 8, (bh * 4 + wid) * 8, kh * 256, lane);
}

// fallback (ws too small): full-K, direct to out
__global__ __launch_bounds__(256, 3)
void vgemm_full(const float* __restrict__ x, const float* __restrict__ Wv,
                float* __restrict__ out) {
    const int lane = threadIdx.x & 63;
    const int wid  = threadIdx.x >> 6;
    const int bid  = blockIdx.x;                // 0..511
    const int xcd  = bid & 7;
    const int r    = bid >> 3;                  // 0..63
    const int nO   = xcd * 32 + (r & 31);
    const int bh   = r >> 5;
    gemm_body<8>(x, Wv, out, nO * 8, (bh * 4 + wid) * 8, 0, lane);
}

__global__ __launch_bounds__(256)
void combine(const float* __restrict__ part, float* __restrict__ out) {
    const int t = blockIdx.x * 256 + threadIdx.x;   // 32768 float4s
    const float4* __restrict__ p = (const float4*)part;
    float4 a = p[t];
    float4 b = p[t + 32768];
    float4 o;
    o.x = a.x + b.x; o.y = a.y + b.y; o.z = a.z + b.z; o.w = a.w + b.w;
    ((float4*)out)[t] = o;
}

extern "C" void kernel_launch(void* const* d_in, const int* in_sizes, int n_in,
                              void* d_out, int out_size, void* d_ws, size_t ws_size,
                              hipStream_t stream) {
    const float* x  = (const float*)d_in[0];   // [64][2048]
    const float* Wv = (const float*)d_in[5];   // [2048][2048]
    float* out = (float*)d_out;                // [64][2048]

    const size_t partBytes = 2ull * 64 * ND * sizeof(float);  // 1 MB
    if (d_ws && ws_size >= partBytes) {
        float* part = (float*)d_ws;
        vgemm_ks<<<1024, 256, 0, stream>>>(x, Wv, part);
        combine<<<128, 256, 0, stream>>>(part, out);
    } else {
        vgemm_full<<<512, 256, 0, stream>>>(x, Wv, out);
    }
}

// Round 17
// 103.735 us; speedup vs baseline: 1.1664x; 1.1664x over previous
//
#include <hip/hip_runtime.h>

// out = x @ Wv^T  (T=1 linear-attention read/scale cancels exactly; verified
// passing r2/4/6/10/14). M=64 N=2048 K=2048 f32.
//
// r15 = r14 with ONE change: __launch_bounds__(256) plain — the (256,3)
// min-waves bound capped VGPRs at ~170 and (theory) forced spills /
// serialized the load pipeline (r14: kernel-side ~34us vs r6's ~13us).
// r4/r10's identical body naturally used 164 VGPR, which already permits
// 3 waves/SIMD; K-split grid (1024 blocks) can then actually occupy them.
//  1. K-split x2: partials to ws, combined by a tiny second kernel.
//  2. Zero-LDS shfl_xor butterfly transpose-reduce epilogue (verified
//     correct on HW in r14: passed, absmax identical to LDS version).
// XCD swizzle: all 4 blocks (2 b-halves x 2 k-halves) of one n-octet group
// land on one XCD; each XCD's W working set = 2MB, L2-resident.

#define ND 2048
#define KD 2048
#define K4 (KD / 4)  // 512

// ---- main GEMM, K-split: NI k4-iters starting at kbase ----
template <int NI>
__device__ __forceinline__ void gemm_body(const float* __restrict__ x,
                                          const float* __restrict__ Wv,
                                          float* __restrict__ dst,
                                          int n0, int b0, int kbase, int lane) {
    const float4* __restrict__ xq = (const float4*)x;
    const float4* __restrict__ wq = (const float4*)Wv;

    float acc[64];  // acc[bb*8+nn]
#pragma unroll
    for (int j = 0; j < 64; ++j) acc[j] = 0.0f;

#pragma unroll
    for (int i = 0; i < NI; ++i) {
        const int k4 = kbase + (i << 6) + lane;
        float4 xr[8], wr[8];
#pragma unroll
        for (int bb = 0; bb < 8; ++bb)
            xr[bb] = xq[(size_t)(b0 + bb) * K4 + k4];
#pragma unroll
        for (int nn = 0; nn < 8; ++nn)
            wr[nn] = wq[(size_t)(n0 + nn) * K4 + k4];
#pragma unroll
        for (int bb = 0; bb < 8; ++bb)
#pragma unroll
            for (int nn = 0; nn < 8; ++nn) {
                float a = acc[bb * 8 + nn];
                a = fmaf(xr[bb].x, wr[nn].x, a);
                a = fmaf(xr[bb].y, wr[nn].y, a);
                a = fmaf(xr[bb].z, wr[nn].z, a);
                a = fmaf(xr[bb].w, wr[nn].w, a);
                acc[bb * 8 + nn] = a;
            }
    }

    // In-register butterfly transpose-reduce (HW-verified r14): after the 6
    // stages, lane j's acc[0] = sum over all 64 lanes of original acc[j].
#pragma unroll
    for (int s = 0; s < 6; ++s) {
        const int bit = (lane >> s) & 1;
#pragma unroll
        for (int u = 0; u < (64 >> (s + 1)); ++u) {
            float snd = bit ? acc[2 * u] : acc[2 * u + 1];
            float kep = bit ? acc[2 * u + 1] : acc[2 * u];
            acc[u] = kep + __shfl_xor(snd, 1 << s, 64);
        }
    }

    dst[(size_t)(b0 + (lane >> 3)) * ND + n0 + (lane & 7)] = acc[0];
}

__global__ __launch_bounds__(256)
void vgemm_ks(const float* __restrict__ x, const float* __restrict__ Wv,
              float* __restrict__ part) {
    const int lane = threadIdx.x & 63;
    const int wid  = threadIdx.x >> 6;          // 0..3
    const int bid  = blockIdx.x;                // 0..1023
    const int xcd  = bid & 7;
    const int r    = bid >> 3;                  // 0..127
    const int nO   = xcd * 32 + (r & 31);       // 0..255; same nO group -> same XCD
    const int bh   = (r >> 5) & 1;              // b-half
    const int kh   = r >> 6;                    // k-half
    gemm_body<4>(x, Wv, part + (size_t)kh * (64 * ND),
                 nO * 8, (bh * 4 + wid) * 8, kh * 256, lane);
}

// fallback (ws too small): full-K, direct to out
__global__ __launch_bounds__(256)
void vgemm_full(const float* __restrict__ x, const float* __restrict__ Wv,
                float* __restrict__ out) {
    const int lane = threadIdx.x & 63;
    const int wid  = threadIdx.x >> 6;
    const int bid  = blockIdx.x;                // 0..511
    const int xcd  = bid & 7;
    const int r    = bid >> 3;                  // 0..63
    const int nO   = xcd * 32 + (r & 31);
    const int bh   = r >> 5;
    gemm_body<8>(x, Wv, out, nO * 8, (bh * 4 + wid) * 8, 0, lane);
}

__global__ __launch_bounds__(256)
void combine(const float* __restrict__ part, float* __restrict__ out) {
    const int t = blockIdx.x * 256 + threadIdx.x;   // 32768 float4s
    const float4* __restrict__ p = (const float4*)part;
    float4 a = p[t];
    float4 b = p[t + 32768];
    float4 o;
    o.x = a.x + b.x; o.y = a.y + b.y; o.z = a.z + b.z; o.w = a.w + b.w;
    ((float4*)out)[t] = o;
}

extern "C" void kernel_launch(void* const* d_in, const int* in_sizes, int n_in,
                              void* d_out, int out_size, void* d_ws, size_t ws_size,
                              hipStream_t stream) {
    const float* x  = (const float*)d_in[0];   // [64][2048]
    const float* Wv = (const float*)d_in[5];   // [2048][2048]
    float* out = (float*)d_out;                // [64][2048]

    const size_t partBytes = 2ull * 64 * ND * sizeof(float);  // 1 MB
    if (d_ws && ws_size >= partBytes) {
        float* part = (float*)d_ws;
        vgemm_ks<<<1024, 256, 0, stream>>>(x, Wv, part);
        combine<<<128, 256, 0, stream>>>(part, out);
    } else {
        vgemm_full<<<512, 256, 0, stream>>>(x, Wv, out);
    }
}